// Round 1
// baseline (292.008 us; speedup 1.0000x reference)
//
#include <hip/hip_runtime.h>
#include <hip/hip_bf16.h>
#include <stdint.h>

typedef __attribute__((ext_vector_type(8))) __bf16 bf16x8;
typedef __attribute__((ext_vector_type(4))) float f32x4;

#define GLOAD_LDS16(gp, lp) __builtin_amdgcn_global_load_lds( \
    (const __attribute__((address_space(1))) void*)(gp),      \
    (__attribute__((address_space(3))) void*)(lp), 16, 0, 0)

__device__ __forceinline__ uint16_t f2bf_rne(float f) {
  uint32_t u = __float_as_uint(f);
  u += 0x7FFFu + ((u >> 16) & 1u);
  return (uint16_t)(u >> 16);
}

// ---------------- f32 -> bf16 conversion (vectorized, 8 elems/thread) -------
__global__ __launch_bounds__(256) void cvt_bf16_kernel(
    const float* __restrict__ src, uint16_t* __restrict__ dst, int n8) {
  int i = blockIdx.x * 256 + threadIdx.x;
  if (i >= n8) return;
  const float4* s4 = (const float4*)src;
  float4 a = s4[2 * i], b = s4[2 * i + 1];
  union { uint16_t u[8]; uint4 v; } o;
  o.u[0] = f2bf_rne(a.x); o.u[1] = f2bf_rne(a.y);
  o.u[2] = f2bf_rne(a.z); o.u[3] = f2bf_rne(a.w);
  o.u[4] = f2bf_rne(b.x); o.u[5] = f2bf_rne(b.y);
  o.u[6] = f2bf_rne(b.z); o.u[7] = f2bf_rne(b.w);
  ((uint4*)dst)[i] = o.v;
}

// ---------------- bf16 GEMM: C[M=2048][N=4096] = A[2048][4096] * B[N][K]^T --
// m97 structure: 128x128 tile, BK=64, 4 waves (2x2, each 64x64), 16x16x32 MFMA,
// global_load_lds width 16. gridDim.y selects {W_Q, W_K}.
__global__ __launch_bounds__(256, 2) void gemm_qk(
    const uint16_t* __restrict__ A,
    const uint16_t* __restrict__ Bq, const uint16_t* __restrict__ Bk,
    float* __restrict__ Cq, float* __restrict__ Ck) {
  const int which = blockIdx.y;
  const uint16_t* Bmat = which ? Bk : Bq;
  float* C = which ? Ck : Cq;

  const int tm = blockIdx.x & 15;   // 16 m-tiles
  const int tn = blockIdx.x >> 4;   // 32 n-tiles
  const int m0 = tm * 128, n0 = tn * 128;

  __shared__ uint16_t As[128 * 64];   // [row][k] linear, 16 KB
  __shared__ uint16_t Bs[128 * 64];   // [col][k] linear, 16 KB

  const int t = threadIdx.x;
  const int lane = t & 63;
  const int w = t >> 6;
  const int wr = w >> 1, wc = w & 1;

  f32x4 acc[4][4] = {};

  const int ld_row = t >> 3;          // 0..31 (+32 per iter)
  const int ld_col = (t & 7) * 8;     // k element offset
  const uint16_t* aptr = A    + (size_t)(m0 + ld_row) * 4096 + ld_col;
  const uint16_t* bptr = Bmat + (size_t)(n0 + ld_row) * 4096 + ld_col;
  uint16_t* as_dst = &As[t * 8];
  uint16_t* bs_dst = &Bs[t * 8];

  for (int kt = 0; kt < 4096 / 64; ++kt) {
#pragma unroll
    for (int it = 0; it < 4; ++it) {
      GLOAD_LDS16(aptr + (size_t)it * 32 * 4096, as_dst + it * 2048);
      GLOAD_LDS16(bptr + (size_t)it * 32 * 4096, bs_dst + it * 2048);
    }
    aptr += 64; bptr += 64;
    __syncthreads();
#pragma unroll
    for (int ks = 0; ks < 2; ++ks) {
      const int ko = ks * 32 + (lane >> 4) * 8;
      const int ar = wr * 64 + (lane & 15);
      const int br = wc * 64 + (lane & 15);
      bf16x8 af[4], bfv[4];
#pragma unroll
      for (int m_ = 0; m_ < 4; ++m_)
        af[m_] = *(const bf16x8*)&As[(ar + m_ * 16) * 64 + ko];
#pragma unroll
      for (int n_ = 0; n_ < 4; ++n_)
        bfv[n_] = *(const bf16x8*)&Bs[(br + n_ * 16) * 64 + ko];
#pragma unroll
      for (int m_ = 0; m_ < 4; ++m_)
#pragma unroll
        for (int n_ = 0; n_ < 4; ++n_)
          acc[m_][n_] = __builtin_amdgcn_mfma_f32_16x16x32_bf16(
              af[m_], bfv[n_], acc[m_][n_], 0, 0, 0);
    }
    __syncthreads();
  }
  // epilogue: C/D layout col=lane&15, row=(lane>>4)*4+j  [m89 verified]
  const int col = n0 + wc * 64 + (lane & 15);
  const int row_b = m0 + wr * 64 + (lane >> 4) * 4;
#pragma unroll
  for (int m_ = 0; m_ < 4; ++m_)
#pragma unroll
    for (int n_ = 0; n_ < 4; ++n_)
#pragma unroll
      for (int j = 0; j < 4; ++j)
        C[(size_t)(row_b + m_ * 16 + j) * 4096 + col + n_ * 16] = acc[m_][n_][j];
}

// ---------------- scores + softmax -> attn[256][64][64] ---------------------
// scores[n,i,j] = (1/sqrt(512)) * sum_{cm,th} Q[b,g8+cm,th*64+i]*K[b,g8+cm,th*64+j]
__global__ __launch_bounds__(256) void attn_scores(
    const float* __restrict__ Q, const float* __restrict__ K,
    float* __restrict__ attn) {
  const int n = blockIdx.x;
  const int b = n >> 3, g = n & 7;
  __shared__ float q_l[4096];
  __shared__ float k_l[4096];
  const int t = threadIdx.x;
  const int j4 = (t & 15) * 4;   // 4 consecutive j per thread
  const int i_base = t >> 4;     // i = i_base + 16*ii
  float acc[4][4] = {};
  const size_t rowbase = ((size_t)(b * 64 + g * 8)) * 4096;

  for (int cm = 0; cm < 8; ++cm) {
    const float4* qrow = (const float4*)(Q + rowbase + (size_t)cm * 4096);
    const float4* krow = (const float4*)(K + rowbase + (size_t)cm * 4096);
    __syncthreads();
#pragma unroll
    for (int r = 0; r < 4; ++r) {
      ((float4*)q_l)[r * 256 + t] = qrow[r * 256 + t];
      ((float4*)k_l)[r * 256 + t] = krow[r * 256 + t];
    }
    __syncthreads();
    for (int th = 0; th < 64; ++th) {
      float4 kv = *(const float4*)&k_l[th * 64 + j4];
#pragma unroll
      for (int ii = 0; ii < 4; ++ii) {
        float qv = q_l[th * 64 + i_base + 16 * ii];
        acc[ii][0] += qv * kv.x; acc[ii][1] += qv * kv.y;
        acc[ii][2] += qv * kv.z; acc[ii][3] += qv * kv.w;
      }
    }
  }
  const float scale = 0.044194173824159216f;  // 1/sqrt(512)
#pragma unroll
  for (int ii = 0; ii < 4; ++ii) {
    float s0 = acc[ii][0] * scale, s1 = acc[ii][1] * scale;
    float s2 = acc[ii][2] * scale, s3 = acc[ii][3] * scale;
    float m = fmaxf(fmaxf(s0, s1), fmaxf(s2, s3));
#pragma unroll
    for (int off = 1; off < 16; off <<= 1) m = fmaxf(m, __shfl_xor(m, off, 64));
    const float l2e = 1.4426950408889634f;
    float e0 = exp2f((s0 - m) * l2e), e1 = exp2f((s1 - m) * l2e);
    float e2 = exp2f((s2 - m) * l2e), e3 = exp2f((s3 - m) * l2e);
    float s = e0 + e1 + e2 + e3;
#pragma unroll
    for (int off = 1; off < 16; off <<= 1) s += __shfl_xor(s, off, 64);
    float inv = 1.0f / s;
    float4 o; o.x = e0 * inv; o.y = e1 * inv; o.z = e2 * inv; o.w = e3 * inv;
    *(float4*)&attn[(size_t)n * 4096 + (size_t)(i_base + 16 * ii) * 64 + j4] = o;
  }
}

// ---------------- V = x-slab * Wv^T ; context = V @ attn ; leaky; scatter ----
__global__ __launch_bounds__(256) void ctx_kernel(
    const float* __restrict__ x, const float* __restrict__ Wv,
    const float* __restrict__ attn, float* __restrict__ out) {
  const int n = blockIdx.x >> 3, ut = blockIdx.x & 7;
  const int b = n >> 3, g = n & 7;
  const int u0 = ut * 64;
  __shared__ float attn_l[64 * 64];  // [c][j]
  __shared__ float wv_l[64 * 64];    // [e][cc]
  __shared__ float x_l[64 * 64];     // [cc][ul]
  __shared__ float v_l[64 * 64];     // [e][ul]
  const int t = threadIdx.x;

#pragma unroll
  for (int r = 0; r < 4; ++r) {
    ((float4*)attn_l)[r * 256 + t] =
        ((const float4*)(attn + (size_t)n * 4096))[r * 256 + t];
    ((float4*)wv_l)[r * 256 + t] = ((const float4*)Wv)[r * 256 + t];
  }
  {
    const float* xbase = x + (size_t)b * 262144 + (size_t)g * 512 + u0;
    const int ul4 = (t & 15) * 4;
    const int cc0 = t >> 4;
#pragma unroll
    for (int r = 0; r < 4; ++r) {
      int cc = cc0 + r * 16;
      *(float4*)&x_l[cc * 64 + ul4] = *(const float4*)&xbase[(size_t)cc * 4096 + ul4];
    }
  }
  __syncthreads();
  {  // V[e][ul] = sum_cc x_l[cc][ul] * Wv[e][cc]
    const int ul = t & 63, e0 = t >> 6;
    float vacc[16];
#pragma unroll
    for (int ee = 0; ee < 16; ++ee) vacc[ee] = 0.f;
    for (int cc = 0; cc < 64; ++cc) {
      float xv = x_l[cc * 64 + ul];
#pragma unroll
      for (int ee = 0; ee < 16; ++ee)
        vacc[ee] += xv * wv_l[(e0 + 4 * ee) * 64 + cc];
    }
#pragma unroll
    for (int ee = 0; ee < 16; ++ee) v_l[(e0 + 4 * ee) * 64 + ul] = vacc[ee];
  }
  __syncthreads();
  {  // ctx[u][j] = sum_c V[c][ul] * attn[c][j]; out[b, g*8+j/8, (j%8)*512+u]
    const int ul = t & 63, j0 = t >> 6;
    float cacc[16];
#pragma unroll
    for (int jj = 0; jj < 16; ++jj) cacc[jj] = 0.f;
    for (int c = 0; c < 64; ++c) {
      float vv = v_l[c * 64 + ul];
#pragma unroll
      for (int jj = 0; jj < 16; ++jj)
        cacc[jj] += vv * attn_l[c * 64 + j0 + 4 * jj];
    }
    float* ob = out + (size_t)b * 262144 + (size_t)g * 8 * 4096;
#pragma unroll
    for (int jj = 0; jj < 16; ++jj) {
      int j = j0 + 4 * jj;
      float v = cacc[jj];
      v = v > 0.f ? v : 0.2f * v;
      ob[(size_t)(j >> 3) * 4096 + (size_t)(j & 7) * 512 + u0 + ul] = v;
    }
  }
}

extern "C" void kernel_launch(void* const* d_in, const int* in_sizes, int n_in,
                              void* d_out, int out_size, void* d_ws, size_t ws_size,
                              hipStream_t stream) {
  const float* z  = (const float*)d_in[0];
  const float* x  = (const float*)d_in[1];
  const float* Wq = (const float*)d_in[2];
  const float* Wk = (const float*)d_in[3];
  const float* Wv = (const float*)d_in[4];
  float* out = (float*)d_out;

  char* ws = (char*)d_ws;
  uint16_t* zb   = (uint16_t*)(ws);                    // 16 MB  (2048x4096 bf16)
  uint16_t* wqb  = (uint16_t*)(ws + 16777216);         // 32 MB
  uint16_t* wkb  = (uint16_t*)(ws + 50331648);         // 32 MB
  float*    Qlin = (float*)(ws + 83886080);            // 32 MB  f32
  float*    Klin = (float*)(ws + 117440512);           // 32 MB  f32
  float*    attn = (float*)(ws + 150994944);           // 4 MB   f32
  // total ws needed: 155,189,248 bytes

  cvt_bf16_kernel<<<4096, 256, 0, stream>>>(z, zb, 8388608 / 8);
  cvt_bf16_kernel<<<8192, 256, 0, stream>>>(Wq, wqb, 16777216 / 8);
  cvt_bf16_kernel<<<8192, 256, 0, stream>>>(Wk, wkb, 16777216 / 8);

  dim3 ggrid(512, 2);
  gemm_qk<<<ggrid, 256, 0, stream>>>(zb, wqb, wkb, Qlin, Klin);

  attn_scores<<<256, 256, 0, stream>>>(Qlin, Klin, attn);
  ctx_kernel<<<2048, 256, 0, stream>>>(x, Wv, attn, out);
}

// Round 2
// 267.305 us; speedup vs baseline: 1.0924x; 1.0924x over previous
//
#include <hip/hip_runtime.h>
#include <hip/hip_bf16.h>
#include <stdint.h>

typedef __attribute__((ext_vector_type(8))) __bf16 bf16x8;
typedef __attribute__((ext_vector_type(4))) float f32x4;

#define GLOAD_LDS16(gp, lp) __builtin_amdgcn_global_load_lds( \
    (const __attribute__((address_space(1))) void*)(gp),      \
    (__attribute__((address_space(3))) void*)(lp), 16, 0, 0)

__device__ __forceinline__ uint16_t f2bf_rne(float f) {
  uint32_t u = __float_as_uint(f);
  u += 0x7FFFu + ((u >> 16) & 1u);
  return (uint16_t)(u >> 16);
}

// ---------------- f32 -> bf16 conversion (vectorized, 8 elems/thread) -------
__global__ __launch_bounds__(256) void cvt_bf16_kernel(
    const float* __restrict__ src, uint16_t* __restrict__ dst, int n8) {
  int i = blockIdx.x * 256 + threadIdx.x;
  if (i >= n8) return;
  const float4* s4 = (const float4*)src;
  float4 a = s4[2 * i], b = s4[2 * i + 1];
  union { uint16_t u[8]; uint4 v; } o;
  o.u[0] = f2bf_rne(a.x); o.u[1] = f2bf_rne(a.y);
  o.u[2] = f2bf_rne(a.z); o.u[3] = f2bf_rne(a.w);
  o.u[4] = f2bf_rne(b.x); o.u[5] = f2bf_rne(b.y);
  o.u[6] = f2bf_rne(b.z); o.u[7] = f2bf_rne(b.w);
  ((uint4*)dst)[i] = o.v;
}

// ---------------- bf16 GEMM, deep-pipelined 256x256 tile ---------------------
// C[2048][4096] = A[2048][4096] * B[4096][4096]^T  (B stored [N][K])
// BK=32, ring of 4 LDS K-tile buffers (32 KB each = A[256][32]+B[256][32] bf16),
// 2 phases/K-tile (16 MFMA each), stage kt+3 during kt, vmcnt(8) steady state.
// LDS XOR swizzle: 16B-slot ^= ((row>>1)&3), applied to global src + ds_read.
// 8 waves: wm=wid>>2 (2), wn=wid&3 (4); per-wave C = 128x64 = acc[8][4] f32x4.
#define PH_BAR() do { asm volatile("" ::: "memory");            \
                      __builtin_amdgcn_s_barrier();             \
                      asm volatile("" ::: "memory"); } while (0)

#define KTILE(kt, DO_STAGE)                                                    \
  do {                                                                         \
    const char* Ab_ = lds + ((kt) & 3) * 32768;                                \
    const char* Bb_ = Ab_ + 16384;                                             \
    bf16x8 aa[4], bb[4];                                                       \
    _Pragma("unroll")                                                          \
    for (int m_ = 0; m_ < 4; ++m_)                                             \
      aa[m_] = *(const bf16x8*)(Ab_ + aoff + m_ * 1024);                       \
    _Pragma("unroll")                                                          \
    for (int n_ = 0; n_ < 4; ++n_)                                             \
      bb[n_] = *(const bf16x8*)(Bb_ + boff + n_ * 1024);                       \
    if (DO_STAGE) {                                                            \
      const int ss_ = ((kt) + 3) & 3;                                          \
      GLOAD_LDS16(aptr  + (size_t)((kt) + 3) * 32, lds + ss_ * 32768 + t16);   \
      GLOAD_LDS16(aptr2 + (size_t)((kt) + 3) * 32,                             \
                  lds + ss_ * 32768 + 8192 + t16);                             \
    }                                                                          \
    PH_BAR();                                                                  \
    asm volatile("s_waitcnt lgkmcnt(0)" ::: "memory");                         \
    __builtin_amdgcn_s_setprio(1);                                             \
    _Pragma("unroll")                                                          \
    for (int m_ = 0; m_ < 4; ++m_)                                             \
      _Pragma("unroll")                                                        \
      for (int n_ = 0; n_ < 4; ++n_)                                           \
        acc[m_][n_] = __builtin_amdgcn_mfma_f32_16x16x32_bf16(                 \
            aa[m_], bb[n_], acc[m_][n_], 0, 0, 0);                             \
    __builtin_amdgcn_s_setprio(0);                                             \
    PH_BAR();                                                                  \
    _Pragma("unroll")                                                          \
    for (int m_ = 0; m_ < 4; ++m_)                                             \
      aa[m_] = *(const bf16x8*)(Ab_ + aoff + 4096 + m_ * 1024);                \
    if (DO_STAGE) {                                                            \
      const int ss_ = ((kt) + 3) & 3;                                          \
      GLOAD_LDS16(bptr  + (size_t)((kt) + 3) * 32,                             \
                  lds + ss_ * 32768 + 16384 + t16);                            \
      GLOAD_LDS16(bptr2 + (size_t)((kt) + 3) * 32,                             \
                  lds + ss_ * 32768 + 24576 + t16);                            \
    }                                                                          \
    PH_BAR();                                                                  \
    asm volatile("s_waitcnt lgkmcnt(0)" ::: "memory");                         \
    __builtin_amdgcn_s_setprio(1);                                             \
    _Pragma("unroll")                                                          \
    for (int m_ = 0; m_ < 4; ++m_)                                             \
      _Pragma("unroll")                                                        \
      for (int n_ = 0; n_ < 4; ++n_)                                           \
        acc[m_ + 4][n_] = __builtin_amdgcn_mfma_f32_16x16x32_bf16(             \
            aa[m_], bb[n_], acc[m_ + 4][n_], 0, 0, 0);                         \
    __builtin_amdgcn_s_setprio(0);                                             \
  } while (0)

__global__ __launch_bounds__(512, 2) void gemm_qk8(
    const uint16_t* __restrict__ A,
    const uint16_t* __restrict__ Bq, const uint16_t* __restrict__ Bk,
    float* __restrict__ Cq, float* __restrict__ Ck) {
  extern __shared__ char lds[];  // 131072 bytes: 4 ring slots x (A 16K + B 16K)

  const int which = blockIdx.y;
  const uint16_t* Bmat = which ? Bk : Bq;
  float* C = which ? Ck : Cq;

  const int tm = blockIdx.x & 7;    // 8 m-tiles -> XCD-aligned A-panel reuse
  const int tn = blockIdx.x >> 3;   // 16 n-tiles
  const int m0 = tm * 256, n0 = tn * 256;

  const int t = threadIdx.x;
  const int lane = t & 63;
  const int w = t >> 6;
  const int wm = w >> 2, wn = w & 3;
  const int t16 = t * 16;

  // staging global pointers (pre-swizzled source k-slot, rule #21 involution)
  const int gsw = (((t & 3) ^ ((t >> 3) & 3)) * 8);
  const uint16_t* aptr  = A    + (size_t)(m0 + (t >> 2)) * 4096 + gsw;
  const uint16_t* aptr2 = aptr + (size_t)128 * 4096;
  const uint16_t* bptr  = Bmat + (size_t)(n0 + (t >> 2)) * 4096 + gsw;
  const uint16_t* bptr2 = bptr + (size_t)128 * 4096;

  // ds_read byte offsets (same XOR swizzle)
  const int sl = ((lane >> 4) ^ ((lane & 15) >> 1)) & 3;
  const int aoff = (wm * 128 + (lane & 15)) * 64 + sl * 16;
  const int boff = (wn * 64 + (lane & 15)) * 64 + sl * 16;

  f32x4 acc[8][4] = {};

  // prologue: stage K-tiles 0,1,2 (12 loads); wait until kt0 complete (8 left)
#pragma unroll
  for (int p = 0; p < 3; ++p) {
    GLOAD_LDS16(aptr  + (size_t)p * 32, lds + p * 32768 + t16);
    GLOAD_LDS16(aptr2 + (size_t)p * 32, lds + p * 32768 + 8192 + t16);
    GLOAD_LDS16(bptr  + (size_t)p * 32, lds + p * 32768 + 16384 + t16);
    GLOAD_LDS16(bptr2 + (size_t)p * 32, lds + p * 32768 + 24576 + t16);
  }
  asm volatile("s_waitcnt vmcnt(8)" ::: "memory");
  PH_BAR();

  for (int kt = 0; kt < 125; ++kt) {
    KTILE(kt, 1);
    asm volatile("s_waitcnt vmcnt(8)" ::: "memory");  // kt+1 fully staged
    PH_BAR();
  }
  KTILE(125, 0);
  asm volatile("s_waitcnt vmcnt(4)" ::: "memory");
  PH_BAR();
  KTILE(126, 0);
  asm volatile("s_waitcnt vmcnt(0)" ::: "memory");
  PH_BAR();
  KTILE(127, 0);

  // epilogue: C/D layout col=lane&15, row=(lane>>4)*4+j
  const int colb = n0 + wn * 64 + (lane & 15);
  const int rowb = m0 + wm * 128 + (lane >> 4) * 4;
#pragma unroll
  for (int m_ = 0; m_ < 8; ++m_)
#pragma unroll
    for (int n_ = 0; n_ < 4; ++n_)
#pragma unroll
      for (int j = 0; j < 4; ++j)
        C[(size_t)(rowb + m_ * 16 + j) * 4096 + colb + n_ * 16] =
            acc[m_][n_][j];
}

// ---------------- scores + softmax -> attn[256][64][64] ---------------------
__global__ __launch_bounds__(256) void attn_scores(
    const float* __restrict__ Q, const float* __restrict__ K,
    float* __restrict__ attn) {
  const int n = blockIdx.x;
  const int b = n >> 3, g = n & 7;
  __shared__ float q_l[4096];
  __shared__ float k_l[4096];
  const int t = threadIdx.x;
  const int j4 = (t & 15) * 4;
  const int i_base = t >> 4;
  float acc[4][4] = {};
  const size_t rowbase = ((size_t)(b * 64 + g * 8)) * 4096;

  for (int cm = 0; cm < 8; ++cm) {
    const float4* qrow = (const float4*)(Q + rowbase + (size_t)cm * 4096);
    const float4* krow = (const float4*)(K + rowbase + (size_t)cm * 4096);
    __syncthreads();
#pragma unroll
    for (int r = 0; r < 4; ++r) {
      ((float4*)q_l)[r * 256 + t] = qrow[r * 256 + t];
      ((float4*)k_l)[r * 256 + t] = krow[r * 256 + t];
    }
    __syncthreads();
    for (int th = 0; th < 64; ++th) {
      float4 kv = *(const float4*)&k_l[th * 64 + j4];
#pragma unroll
      for (int ii = 0; ii < 4; ++ii) {
        float qv = q_l[th * 64 + i_base + 16 * ii];
        acc[ii][0] += qv * kv.x; acc[ii][1] += qv * kv.y;
        acc[ii][2] += qv * kv.z; acc[ii][3] += qv * kv.w;
      }
    }
  }
  const float scale = 0.044194173824159216f;  // 1/sqrt(512)
#pragma unroll
  for (int ii = 0; ii < 4; ++ii) {
    float s0 = acc[ii][0] * scale, s1 = acc[ii][1] * scale;
    float s2 = acc[ii][2] * scale, s3 = acc[ii][3] * scale;
    float m = fmaxf(fmaxf(s0, s1), fmaxf(s2, s3));
#pragma unroll
    for (int off = 1; off < 16; off <<= 1) m = fmaxf(m, __shfl_xor(m, off, 64));
    const float l2e = 1.4426950408889634f;
    float e0 = exp2f((s0 - m) * l2e), e1 = exp2f((s1 - m) * l2e);
    float e2 = exp2f((s2 - m) * l2e), e3 = exp2f((s3 - m) * l2e);
    float s = e0 + e1 + e2 + e3;
#pragma unroll
    for (int off = 1; off < 16; off <<= 1) s += __shfl_xor(s, off, 64);
    float inv = 1.0f / s;
    float4 o; o.x = e0 * inv; o.y = e1 * inv; o.z = e2 * inv; o.w = e3 * inv;
    *(float4*)&attn[(size_t)n * 4096 + (size_t)(i_base + 16 * ii) * 64 + j4] = o;
  }
}

// ---------------- V = x-slab * Wv^T ; context = V @ attn ; leaky; scatter ----
__global__ __launch_bounds__(256) void ctx_kernel(
    const float* __restrict__ x, const float* __restrict__ Wv,
    const float* __restrict__ attn, float* __restrict__ out) {
  const int n = blockIdx.x >> 3, ut = blockIdx.x & 7;
  const int b = n >> 3, g = n & 7;
  const int u0 = ut * 64;
  __shared__ float attn_l[64 * 64];
  __shared__ float wv_l[64 * 64];
  __shared__ float x_l[64 * 64];
  __shared__ float v_l[64 * 64];
  const int t = threadIdx.x;

#pragma unroll
  for (int r = 0; r < 4; ++r) {
    ((float4*)attn_l)[r * 256 + t] =
        ((const float4*)(attn + (size_t)n * 4096))[r * 256 + t];
    ((float4*)wv_l)[r * 256 + t] = ((const float4*)Wv)[r * 256 + t];
  }
  {
    const float* xbase = x + (size_t)b * 262144 + (size_t)g * 512 + u0;
    const int ul4 = (t & 15) * 4;
    const int cc0 = t >> 4;
#pragma unroll
    for (int r = 0; r < 4; ++r) {
      int cc = cc0 + r * 16;
      *(float4*)&x_l[cc * 64 + ul4] = *(const float4*)&xbase[(size_t)cc * 4096 + ul4];
    }
  }
  __syncthreads();
  {
    const int ul = t & 63, e0 = t >> 6;
    float vacc[16];
#pragma unroll
    for (int ee = 0; ee < 16; ++ee) vacc[ee] = 0.f;
    for (int cc = 0; cc < 64; ++cc) {
      float xv = x_l[cc * 64 + ul];
#pragma unroll
      for (int ee = 0; ee < 16; ++ee)
        vacc[ee] += xv * wv_l[(e0 + 4 * ee) * 64 + cc];
    }
#pragma unroll
    for (int ee = 0; ee < 16; ++ee) v_l[(e0 + 4 * ee) * 64 + ul] = vacc[ee];
  }
  __syncthreads();
  {
    const int ul = t & 63, j0 = t >> 6;
    float cacc[16];
#pragma unroll
    for (int jj = 0; jj < 16; ++jj) cacc[jj] = 0.f;
    for (int c = 0; c < 64; ++c) {
      float vv = v_l[c * 64 + ul];
#pragma unroll
      for (int jj = 0; jj < 16; ++jj)
        cacc[jj] += vv * attn_l[c * 64 + j0 + 4 * jj];
    }
    float* ob = out + (size_t)b * 262144 + (size_t)g * 8 * 4096;
#pragma unroll
    for (int jj = 0; jj < 16; ++jj) {
      int j = j0 + 4 * jj;
      float v = cacc[jj];
      v = v > 0.f ? v : 0.2f * v;
      ob[(size_t)(j >> 3) * 4096 + (size_t)(j & 7) * 512 + u0 + ul] = v;
    }
  }
}

extern "C" void kernel_launch(void* const* d_in, const int* in_sizes, int n_in,
                              void* d_out, int out_size, void* d_ws, size_t ws_size,
                              hipStream_t stream) {
  const float* z  = (const float*)d_in[0];
  const float* x  = (const float*)d_in[1];
  const float* Wq = (const float*)d_in[2];
  const float* Wk = (const float*)d_in[3];
  const float* Wv = (const float*)d_in[4];
  float* out = (float*)d_out;

  char* ws = (char*)d_ws;
  uint16_t* zb   = (uint16_t*)(ws);
  uint16_t* wqb  = (uint16_t*)(ws + 16777216);
  uint16_t* wkb  = (uint16_t*)(ws + 50331648);
  float*    Qlin = (float*)(ws + 83886080);
  float*    Klin = (float*)(ws + 117440512);
  float*    attn = (float*)(ws + 150994944);

  cvt_bf16_kernel<<<4096, 256, 0, stream>>>(z, zb, 8388608 / 8);
  cvt_bf16_kernel<<<8192, 256, 0, stream>>>(Wq, wqb, 16777216 / 8);
  cvt_bf16_kernel<<<8192, 256, 0, stream>>>(Wk, wkb, 16777216 / 8);

  (void)hipFuncSetAttribute((const void*)gemm_qk8,
                            hipFuncAttributeMaxDynamicSharedMemorySize, 131072);
  dim3 ggrid(128, 2);
  gemm_qk8<<<ggrid, 512, 131072, stream>>>(zb, wqb, wkb, Qlin, Klin);

  attn_scores<<<256, 256, 0, stream>>>(Qlin, Klin, attn);
  ctx_kernel<<<2048, 256, 0, stream>>>(x, Wv, attn, out);
}

// Round 4
// 247.247 us; speedup vs baseline: 1.1810x; 1.0811x over previous
//
#include <hip/hip_runtime.h>
#include <hip/hip_bf16.h>
#include <stdint.h>

typedef __attribute__((ext_vector_type(8))) __bf16 bf16x8;
typedef __attribute__((ext_vector_type(4))) float f32x4;

#define GLOAD_LDS16(gp, lp) __builtin_amdgcn_global_load_lds( \
    (const __attribute__((address_space(1))) void*)(gp),      \
    (__attribute__((address_space(3))) void*)(lp), 16, 0, 0)

__device__ __forceinline__ uint16_t f2bf_rne(float f) {
  uint32_t u = __float_as_uint(f);
  u += 0x7FFFu + ((u >> 16) & 1u);
  return (uint16_t)(u >> 16);
}

// ---------------- f32 -> bf16 conversion (vectorized, 8 elems/thread) -------
__global__ __launch_bounds__(256) void cvt_bf16_kernel(
    const float* __restrict__ src, uint16_t* __restrict__ dst, int n8) {
  int i = blockIdx.x * 256 + threadIdx.x;
  if (i >= n8) return;
  const float4* s4 = (const float4*)src;
  float4 a = s4[2 * i], b = s4[2 * i + 1];
  union { uint16_t u[8]; uint4 v; } o;
  o.u[0] = f2bf_rne(a.x); o.u[1] = f2bf_rne(a.y);
  o.u[2] = f2bf_rne(a.z); o.u[3] = f2bf_rne(a.w);
  o.u[4] = f2bf_rne(b.x); o.u[5] = f2bf_rne(b.y);
  o.u[6] = f2bf_rne(b.z); o.u[7] = f2bf_rne(b.w);
  ((uint4*)dst)[i] = o.v;
}

// ---------------- bf16 GEMM, deep-pipelined 256x256 tile ---------------------
// R2-validated schedule (ring-4 BK=32, counted vmcnt, setprio, XOR swizzle).
// Epilogue writes bf16 (Q/K feed the MFMA scores kernel only).
#define PH_BAR() do { asm volatile("" ::: "memory");            \
                      __builtin_amdgcn_s_barrier();             \
                      asm volatile("" ::: "memory"); } while (0)

#define KTILE(kt, DO_STAGE)                                                    \
  do {                                                                         \
    const char* Ab_ = lds + ((kt) & 3) * 32768;                                \
    const char* Bb_ = Ab_ + 16384;                                             \
    bf16x8 aa[4], bb[4];                                                       \
    _Pragma("unroll")                                                          \
    for (int m_ = 0; m_ < 4; ++m_)                                             \
      aa[m_] = *(const bf16x8*)(Ab_ + aoff + m_ * 1024);                       \
    _Pragma("unroll")                                                          \
    for (int n_ = 0; n_ < 4; ++n_)                                             \
      bb[n_] = *(const bf16x8*)(Bb_ + boff + n_ * 1024);                       \
    if (DO_STAGE) {                                                            \
      const int ss_ = ((kt) + 3) & 3;                                          \
      GLOAD_LDS16(aptr  + (size_t)((kt) + 3) * 32, lds + ss_ * 32768 + t16);   \
      GLOAD_LDS16(aptr2 + (size_t)((kt) + 3) * 32,                             \
                  lds + ss_ * 32768 + 8192 + t16);                             \
    }                                                                          \
    PH_BAR();                                                                  \
    asm volatile("s_waitcnt lgkmcnt(0)" ::: "memory");                         \
    __builtin_amdgcn_s_setprio(1);                                             \
    _Pragma("unroll")                                                          \
    for (int m_ = 0; m_ < 4; ++m_)                                             \
      _Pragma("unroll")                                                        \
      for (int n_ = 0; n_ < 4; ++n_)                                           \
        acc[m_][n_] = __builtin_amdgcn_mfma_f32_16x16x32_bf16(                 \
            aa[m_], bb[n_], acc[m_][n_], 0, 0, 0);                             \
    __builtin_amdgcn_s_setprio(0);                                             \
    PH_BAR();                                                                  \
    _Pragma("unroll")                                                          \
    for (int m_ = 0; m_ < 4; ++m_)                                             \
      aa[m_] = *(const bf16x8*)(Ab_ + aoff + 4096 + m_ * 1024);                \
    if (DO_STAGE) {                                                            \
      const int ss_ = ((kt) + 3) & 3;                                          \
      GLOAD_LDS16(bptr  + (size_t)((kt) + 3) * 32,                             \
                  lds + ss_ * 32768 + 16384 + t16);                            \
      GLOAD_LDS16(bptr2 + (size_t)((kt) + 3) * 32,                             \
                  lds + ss_ * 32768 + 24576 + t16);                            \
    }                                                                          \
    PH_BAR();                                                                  \
    asm volatile("s_waitcnt lgkmcnt(0)" ::: "memory");                         \
    __builtin_amdgcn_s_setprio(1);                                             \
    _Pragma("unroll")                                                          \
    for (int m_ = 0; m_ < 4; ++m_)                                             \
      _Pragma("unroll")                                                        \
      for (int n_ = 0; n_ < 4; ++n_)                                           \
        acc[m_ + 4][n_] = __builtin_amdgcn_mfma_f32_16x16x32_bf16(             \
            aa[m_], bb[n_], acc[m_ + 4][n_], 0, 0, 0);                         \
    __builtin_amdgcn_s_setprio(0);                                             \
  } while (0)

__global__ __launch_bounds__(512, 2) void gemm_qk8(
    const uint16_t* __restrict__ A,
    const uint16_t* __restrict__ Bq, const uint16_t* __restrict__ Bk,
    uint16_t* __restrict__ Cq, uint16_t* __restrict__ Ck) {
  extern __shared__ char lds[];  // 131072 bytes: 4 ring slots x (A 16K + B 16K)

  const int which = blockIdx.y;
  const uint16_t* Bmat = which ? Bk : Bq;
  uint16_t* C = which ? Ck : Cq;

  const int tm = blockIdx.x & 7;    // 8 m-tiles -> XCD-aligned A-panel reuse
  const int tn = blockIdx.x >> 3;   // 16 n-tiles
  const int m0 = tm * 256, n0 = tn * 256;

  const int t = threadIdx.x;
  const int lane = t & 63;
  const int w = t >> 6;
  const int wm = w >> 2, wn = w & 3;
  const int t16 = t * 16;

  const int gsw = (((t & 3) ^ ((t >> 3) & 3)) * 8);
  const uint16_t* aptr  = A    + (size_t)(m0 + (t >> 2)) * 4096 + gsw;
  const uint16_t* aptr2 = aptr + (size_t)128 * 4096;
  const uint16_t* bptr  = Bmat + (size_t)(n0 + (t >> 2)) * 4096 + gsw;
  const uint16_t* bptr2 = bptr + (size_t)128 * 4096;

  const int sl = ((lane >> 4) ^ ((lane & 15) >> 1)) & 3;
  const int aoff = (wm * 128 + (lane & 15)) * 64 + sl * 16;
  const int boff = (wn * 64 + (lane & 15)) * 64 + sl * 16;

  f32x4 acc[8][4] = {};

#pragma unroll
  for (int p = 0; p < 3; ++p) {
    GLOAD_LDS16(aptr  + (size_t)p * 32, lds + p * 32768 + t16);
    GLOAD_LDS16(aptr2 + (size_t)p * 32, lds + p * 32768 + 8192 + t16);
    GLOAD_LDS16(bptr  + (size_t)p * 32, lds + p * 32768 + 16384 + t16);
    GLOAD_LDS16(bptr2 + (size_t)p * 32, lds + p * 32768 + 24576 + t16);
  }
  asm volatile("s_waitcnt vmcnt(8)" ::: "memory");
  PH_BAR();

  for (int kt = 0; kt < 125; ++kt) {
    KTILE(kt, 1);
    asm volatile("s_waitcnt vmcnt(8)" ::: "memory");
    PH_BAR();
  }
  KTILE(125, 0);
  asm volatile("s_waitcnt vmcnt(4)" ::: "memory");
  PH_BAR();
  KTILE(126, 0);
  asm volatile("s_waitcnt vmcnt(0)" ::: "memory");
  PH_BAR();
  KTILE(127, 0);

  // epilogue: C/D layout col=lane&15, row=(lane>>4)*4+j ; store bf16
  const int colb = n0 + wn * 64 + (lane & 15);
  const int rowb = m0 + wm * 128 + (lane >> 4) * 4;
#pragma unroll
  for (int m_ = 0; m_ < 8; ++m_)
#pragma unroll
    for (int n_ = 0; n_ < 4; ++n_)
#pragma unroll
      for (int j = 0; j < 4; ++j)
        C[(size_t)(rowb + m_ * 16 + j) * 4096 + colb + n_ * 16] =
            f2bf_rne(acc[m_][n_][j]);
}

// ---------------- MFMA scores + softmax -> attn[256][64][64] f32 ------------
// Per head n: Qh = Qb[n*32768 ..] is [512 d][64 i] bf16 (i-fastest).
// scores[i,j] = (1/sqrt(512)) sum_d Qh[d][i] Kh[d][j].
// LDS chunk [64 th][64 i], granule rotation rot(th) = (th + 2*(th>>3)) & 7
// (units of 8 elems): per-instruction group rotations {0,2,4,6}+e are disjoint
// -> pure 2-way bank sharing (free). Rotation applied to the global SOURCE
// granule (linear LDS dest, rule #21); same involution on the read side.
__device__ __forceinline__ bf16x8 load_frag_rot(const uint16_t* buf,
                                                int ij, int thb) {
  union { uint16_t u[8]; bf16x8 v; } r;
#pragma unroll
  for (int e = 0; e < 8; ++e) {
    const int th = thb + e;
    const int rot = (th + 2 * (th >> 3)) & 7;
    const int irot = (ij + rot * 8) & 63;
    r.u[e] = buf[th * 64 + irot];
  }
  return r.v;
}

__global__ __launch_bounds__(256) void attn_scores_mfma(
    const uint16_t* __restrict__ Qb, const uint16_t* __restrict__ Kb,
    float* __restrict__ attn) {
  const int n = blockIdx.x;
  __shared__ uint16_t q_l[2][4096];
  __shared__ uint16_t k_l[2][4096];
  __shared__ float scores_l[64 * 68];

  const int t = threadIdx.x;
  const int lane = t & 63;
  const int w = t >> 6;
  const int i0w = (w >> 1) * 32, j0w = (w & 1) * 32;

  const uint16_t* Qn = Qb + (size_t)n * 32768;
  const uint16_t* Kn = Kb + (size_t)n * 32768;

  // per-thread staging granules: g = t and t+256 (512 granules = 64 rows)
  const int g1 = t, g2 = t + 256;
  const int th1 = g1 >> 3, th2 = g2 >> 3;
  const int s1 = (((g1 & 7) - ((th1 + 2 * (th1 >> 3)) & 7)) & 7);
  const int s2 = (((g2 & 7) - ((th2 + 2 * (th2 >> 3)) & 7)) & 7);
  const size_t so1 = (size_t)th1 * 64 + s1 * 8;
  const size_t so2 = (size_t)th2 * 64 + s2 * 8;

#define STAGE_CH(bf, cm)                                                    \
  do {                                                                      \
    const size_t co_ = (size_t)(cm) * 4096;                                 \
    GLOAD_LDS16(Qn + co_ + so1, (char*)&q_l[bf][0] + g1 * 16);              \
    GLOAD_LDS16(Qn + co_ + so2, (char*)&q_l[bf][0] + g2 * 16);              \
    GLOAD_LDS16(Kn + co_ + so1, (char*)&k_l[bf][0] + g1 * 16);              \
    GLOAD_LDS16(Kn + co_ + so2, (char*)&k_l[bf][0] + g2 * 16);              \
  } while (0)

  f32x4 acc[2][2] = {};

  STAGE_CH(0, 0);
  asm volatile("s_waitcnt vmcnt(0)" ::: "memory");
  __syncthreads();

  for (int cm = 0; cm < 8; ++cm) {
    const int bf = cm & 1;
    if (cm < 7) STAGE_CH(bf ^ 1, cm + 1);
#pragma unroll
    for (int ks = 0; ks < 2; ++ks) {
      const int thb = ks * 32 + (lane >> 4) * 8;
      bf16x8 aa0 = load_frag_rot(&q_l[bf][0], i0w + (lane & 15), thb);
      bf16x8 aa1 = load_frag_rot(&q_l[bf][0], i0w + 16 + (lane & 15), thb);
      bf16x8 bb0 = load_frag_rot(&k_l[bf][0], j0w + (lane & 15), thb);
      bf16x8 bb1 = load_frag_rot(&k_l[bf][0], j0w + 16 + (lane & 15), thb);
      acc[0][0] = __builtin_amdgcn_mfma_f32_16x16x32_bf16(aa0, bb0, acc[0][0], 0, 0, 0);
      acc[0][1] = __builtin_amdgcn_mfma_f32_16x16x32_bf16(aa0, bb1, acc[0][1], 0, 0, 0);
      acc[1][0] = __builtin_amdgcn_mfma_f32_16x16x32_bf16(aa1, bb0, acc[1][0], 0, 0, 0);
      acc[1][1] = __builtin_amdgcn_mfma_f32_16x16x32_bf16(aa1, bb1, acc[1][1], 0, 0, 0);
    }
    asm volatile("s_waitcnt vmcnt(0)" ::: "memory");
    __syncthreads();
  }
#undef STAGE_CH

  // scatter scores into LDS [64][68] f32
#pragma unroll
  for (int fi = 0; fi < 2; ++fi)
#pragma unroll
    for (int fj = 0; fj < 2; ++fj)
#pragma unroll
      for (int jr = 0; jr < 4; ++jr) {
        const int i = i0w + fi * 16 + (lane >> 4) * 4 + jr;
        const int j = j0w + fj * 16 + (lane & 15);
        scores_l[i * 68 + j] = acc[fi][fj][jr];
      }
  __syncthreads();

  // softmax over j (64) per row i; 4 threads per row; all-constant indexing
  {
    const int i = t >> 2, jg = t & 3;
    float pv[16];
    *(float4*)(pv + 0)  = *(const float4*)&scores_l[i * 68 + jg * 16 + 0];
    *(float4*)(pv + 4)  = *(const float4*)&scores_l[i * 68 + jg * 16 + 4];
    *(float4*)(pv + 8)  = *(const float4*)&scores_l[i * 68 + jg * 16 + 8];
    *(float4*)(pv + 12) = *(const float4*)&scores_l[i * 68 + jg * 16 + 12];
    float m = pv[0];
#pragma unroll
    for (int q = 1; q < 16; ++q) m = fmaxf(m, pv[q]);
    m = fmaxf(m, __shfl_xor(m, 1, 64));
    m = fmaxf(m, __shfl_xor(m, 2, 64));
    const float sc = 0.044194173824159216f * 1.4426950408889634f;  // /sqrt(512)*log2e
    float e[16];
    float ssum = 0.f;
#pragma unroll
    for (int q = 0; q < 16; ++q) {
      e[q] = exp2f((pv[q] - m) * sc);
      ssum += e[q];
    }
    ssum += __shfl_xor(ssum, 1, 64);
    ssum += __shfl_xor(ssum, 2, 64);
    const float inv = 1.0f / ssum;
    float ov[16];
#pragma unroll
    for (int q = 0; q < 16; ++q) ov[q] = e[q] * inv;
    float* dst = attn + (size_t)n * 4096 + i * 64 + jg * 16;
    *(float4*)(dst + 0)  = *(float4*)(ov + 0);
    *(float4*)(dst + 4)  = *(float4*)(ov + 4);
    *(float4*)(dst + 8)  = *(float4*)(ov + 8);
    *(float4*)(dst + 12) = *(float4*)(ov + 12);
  }
}

// ---------------- V = x-slab * Wv^T ; context = V @ attn ; leaky; scatter ----
__global__ __launch_bounds__(256) void ctx_kernel(
    const float* __restrict__ x, const float* __restrict__ Wv,
    const float* __restrict__ attn, float* __restrict__ out) {
  const int n = blockIdx.x >> 3, ut = blockIdx.x & 7;
  const int b = n >> 3, g = n & 7;
  const int u0 = ut * 64;
  __shared__ float attn_l[64 * 64];
  __shared__ float wv_l[64 * 64];
  __shared__ float x_l[64 * 64];
  __shared__ float v_l[64 * 64];
  const int t = threadIdx.x;

#pragma unroll
  for (int r = 0; r < 4; ++r) {
    ((float4*)attn_l)[r * 256 + t] =
        ((const float4*)(attn + (size_t)n * 4096))[r * 256 + t];
    ((float4*)wv_l)[r * 256 + t] = ((const float4*)Wv)[r * 256 + t];
  }
  {
    const float* xbase = x + (size_t)b * 262144 + (size_t)g * 512 + u0;
    const int ul4 = (t & 15) * 4;
    const int cc0 = t >> 4;
#pragma unroll
    for (int r = 0; r < 4; ++r) {
      int cc = cc0 + r * 16;
      *(float4*)&x_l[cc * 64 + ul4] = *(const float4*)&xbase[(size_t)cc * 4096 + ul4];
    }
  }
  __syncthreads();
  {
    const int ul = t & 63, e0 = t >> 6;
    float vacc[16];
#pragma unroll
    for (int ee = 0; ee < 16; ++ee) vacc[ee] = 0.f;
    for (int cc = 0; cc < 64; ++cc) {
      float xv = x_l[cc * 64 + ul];
#pragma unroll
      for (int ee = 0; ee < 16; ++ee)
        vacc[ee] += xv * wv_l[(e0 + 4 * ee) * 64 + cc];
    }
#pragma unroll
    for (int ee = 0; ee < 16; ++ee) v_l[(e0 + 4 * ee) * 64 + ul] = vacc[ee];
  }
  __syncthreads();
  {
    const int ul = t & 63, j0 = t >> 6;
    float cacc[16];
#pragma unroll
    for (int jj = 0; jj < 16; ++jj) cacc[jj] = 0.f;
    for (int c = 0; c < 64; ++c) {
      float vv = v_l[c * 64 + ul];
#pragma unroll
      for (int jj = 0; jj < 16; ++jj)
        cacc[jj] += vv * attn_l[c * 64 + j0 + 4 * jj];
    }
    float* ob = out + (size_t)b * 262144 + (size_t)g * 8 * 4096;
#pragma unroll
    for (int jj = 0; jj < 16; ++jj) {
      int j = j0 + 4 * jj;
      float v = cacc[jj];
      v = v > 0.f ? v : 0.2f * v;
      ob[(size_t)(j >> 3) * 4096 + (size_t)(j & 7) * 512 + u0 + ul] = v;
    }
  }
}

extern "C" void kernel_launch(void* const* d_in, const int* in_sizes, int n_in,
                              void* d_out, int out_size, void* d_ws, size_t ws_size,
                              hipStream_t stream) {
  const float* z  = (const float*)d_in[0];
  const float* x  = (const float*)d_in[1];
  const float* Wq = (const float*)d_in[2];
  const float* Wk = (const float*)d_in[3];
  const float* Wv = (const float*)d_in[4];
  float* out = (float*)d_out;

  char* ws = (char*)d_ws;
  uint16_t* zb   = (uint16_t*)(ws);                  // 16 MB
  uint16_t* wqb  = (uint16_t*)(ws + 16777216);       // 32 MB
  uint16_t* wkb  = (uint16_t*)(ws + 50331648);       // 32 MB
  uint16_t* qbo  = (uint16_t*)(ws + 83886080);       // 16 MB bf16 Q
  uint16_t* kbo  = (uint16_t*)(ws + 100663296);      // 16 MB bf16 K
  float*    attn = (float*)(ws + 117440512);         // 4 MB f32
  // total ws: 121,634,816 bytes

  cvt_bf16_kernel<<<4096, 256, 0, stream>>>(z, zb, 8388608 / 8);
  cvt_bf16_kernel<<<8192, 256, 0, stream>>>(Wq, wqb, 16777216 / 8);
  cvt_bf16_kernel<<<8192, 256, 0, stream>>>(Wk, wkb, 16777216 / 8);

  (void)hipFuncSetAttribute((const void*)gemm_qk8,
                            hipFuncAttributeMaxDynamicSharedMemorySize, 131072);
  dim3 ggrid(128, 2);
  gemm_qk8<<<ggrid, 512, 131072, stream>>>(zb, wqb, wkb, qbo, kbo);

  attn_scores_mfma<<<256, 256, 0, stream>>>(qbo, kbo, attn);
  ctx_kernel<<<2048, 256, 0, stream>>>(x, Wv, attn, out);
}

// Round 5
// 241.656 us; speedup vs baseline: 1.2084x; 1.0231x over previous
//
#include <hip/hip_runtime.h>
#include <hip/hip_bf16.h>
#include <stdint.h>

typedef __attribute__((ext_vector_type(8))) __bf16 bf16x8;
typedef __attribute__((ext_vector_type(4))) float f32x4;

#define GLOAD_LDS16(gp, lp) __builtin_amdgcn_global_load_lds( \
    (const __attribute__((address_space(1))) void*)(gp),      \
    (__attribute__((address_space(3))) void*)(lp), 16, 0, 0)

__device__ __forceinline__ uint16_t f2bf_rne(float f) {
  uint32_t u = __float_as_uint(f);
  u += 0x7FFFu + ((u >> 16) & 1u);
  return (uint16_t)(u >> 16);
}

// ---------------- fused f32 -> bf16 conversion (z, Wq, Wk in one launch) ----
__global__ __launch_bounds__(256) void cvt_all(
    const float* __restrict__ z, const float* __restrict__ wq,
    const float* __restrict__ wk, uint16_t* __restrict__ zb,
    uint16_t* __restrict__ wqb, uint16_t* __restrict__ wkb) {
  const int bid = blockIdx.x;
  const float* src;
  uint16_t* dst;
  int i;
  if (bid < 4096)        { src = z;  dst = zb;  i = bid * 256 + threadIdx.x; }
  else if (bid < 12288)  { src = wq; dst = wqb; i = (bid - 4096) * 256 + threadIdx.x; }
  else                   { src = wk; dst = wkb; i = (bid - 12288) * 256 + threadIdx.x; }
  const float4* s4 = (const float4*)src;
  float4 a = s4[2 * i], b = s4[2 * i + 1];
  union { uint16_t u[8]; uint4 v; } o;
  o.u[0] = f2bf_rne(a.x); o.u[1] = f2bf_rne(a.y);
  o.u[2] = f2bf_rne(a.z); o.u[3] = f2bf_rne(a.w);
  o.u[4] = f2bf_rne(b.x); o.u[5] = f2bf_rne(b.y);
  o.u[6] = f2bf_rne(b.z); o.u[7] = f2bf_rne(b.w);
  ((uint4*)dst)[i] = o.v;
}

// ---------------- bf16 GEMM, deep-pipelined 256x256 tile ---------------------
// R2/R4-validated dataflow (ring-4 BK=32, depth-3 prefetch, counted vmcnt,
// XOR swizzle, bf16 epilogue). R5 change: ONE barrier per K-tile — interior
// barriers/lgkmcnt removed; the K-tile is a single basic block so the compiler
// interleaves ds_reads with MFMAs using counted lgkmcnt (overlap LDS & MFMA).
#define PH_BAR() do { asm volatile("" ::: "memory");            \
                      __builtin_amdgcn_s_barrier();             \
                      asm volatile("" ::: "memory"); } while (0)

#define KTILE(kt, DO_STAGE)                                                    \
  do {                                                                         \
    const char* Ab_ = lds + ((kt) & 3) * 32768;                                \
    const char* Bb_ = Ab_ + 16384;                                             \
    bf16x8 aa0[4], aa1[4], bb[4];                                              \
    _Pragma("unroll")                                                          \
    for (int n_ = 0; n_ < 4; ++n_)                                             \
      bb[n_] = *(const bf16x8*)(Bb_ + boff + n_ * 1024);                       \
    _Pragma("unroll")                                                          \
    for (int m_ = 0; m_ < 4; ++m_)                                             \
      aa0[m_] = *(const bf16x8*)(Ab_ + aoff + m_ * 1024);                      \
    if (DO_STAGE) {                                                            \
      const int ss_ = ((kt) + 3) & 3;                                          \
      GLOAD_LDS16(aptr  + (size_t)((kt) + 3) * 32, lds + ss_ * 32768 + t16);   \
      GLOAD_LDS16(aptr2 + (size_t)((kt) + 3) * 32,                             \
                  lds + ss_ * 32768 + 8192 + t16);                             \
    }                                                                          \
    _Pragma("unroll")                                                          \
    for (int m_ = 0; m_ < 4; ++m_)                                             \
      aa1[m_] = *(const bf16x8*)(Ab_ + aoff + 4096 + m_ * 1024);               \
    if (DO_STAGE) {                                                            \
      const int ss_ = ((kt) + 3) & 3;                                          \
      GLOAD_LDS16(bptr  + (size_t)((kt) + 3) * 32,                             \
                  lds + ss_ * 32768 + 16384 + t16);                            \
      GLOAD_LDS16(bptr2 + (size_t)((kt) + 3) * 32,                             \
                  lds + ss_ * 32768 + 24576 + t16);                            \
    }                                                                          \
    __builtin_amdgcn_s_setprio(1);                                             \
    _Pragma("unroll")                                                          \
    for (int m_ = 0; m_ < 4; ++m_)                                             \
      _Pragma("unroll")                                                        \
      for (int n_ = 0; n_ < 4; ++n_)                                           \
        acc[m_][n_] = __builtin_amdgcn_mfma_f32_16x16x32_bf16(                 \
            aa0[m_], bb[n_], acc[m_][n_], 0, 0, 0);                            \
    _Pragma("unroll")                                                          \
    for (int m_ = 0; m_ < 4; ++m_)                                             \
      _Pragma("unroll")                                                        \
      for (int n_ = 0; n_ < 4; ++n_)                                           \
        acc[m_ + 4][n_] = __builtin_amdgcn_mfma_f32_16x16x32_bf16(             \
            aa1[m_], bb[n_], acc[m_ + 4][n_], 0, 0, 0);                        \
    __builtin_amdgcn_s_setprio(0);                                             \
  } while (0)

__global__ __launch_bounds__(512, 2) void gemm_qk8(
    const uint16_t* __restrict__ A,
    const uint16_t* __restrict__ Bq, const uint16_t* __restrict__ Bk,
    uint16_t* __restrict__ Cq, uint16_t* __restrict__ Ck) {
  extern __shared__ char lds[];  // 131072 bytes: 4 ring slots x (A 16K + B 16K)

  const int which = blockIdx.y;
  const uint16_t* Bmat = which ? Bk : Bq;
  uint16_t* C = which ? Ck : Cq;

  const int tm = blockIdx.x & 7;    // 8 m-tiles -> XCD-aligned A-panel reuse
  const int tn = blockIdx.x >> 3;   // 16 n-tiles
  const int m0 = tm * 256, n0 = tn * 256;

  const int t = threadIdx.x;
  const int lane = t & 63;
  const int w = t >> 6;
  const int wm = w >> 2, wn = w & 3;
  const int t16 = t * 16;

  const int gsw = (((t & 3) ^ ((t >> 3) & 3)) * 8);
  const uint16_t* aptr  = A    + (size_t)(m0 + (t >> 2)) * 4096 + gsw;
  const uint16_t* aptr2 = aptr + (size_t)128 * 4096;
  const uint16_t* bptr  = Bmat + (size_t)(n0 + (t >> 2)) * 4096 + gsw;
  const uint16_t* bptr2 = bptr + (size_t)128 * 4096;

  const int sl = ((lane >> 4) ^ ((lane & 15) >> 1)) & 3;
  const int aoff = (wm * 128 + (lane & 15)) * 64 + sl * 16;
  const int boff = (wn * 64 + (lane & 15)) * 64 + sl * 16;

  f32x4 acc[8][4] = {};

#pragma unroll
  for (int p = 0; p < 3; ++p) {
    GLOAD_LDS16(aptr  + (size_t)p * 32, lds + p * 32768 + t16);
    GLOAD_LDS16(aptr2 + (size_t)p * 32, lds + p * 32768 + 8192 + t16);
    GLOAD_LDS16(bptr  + (size_t)p * 32, lds + p * 32768 + 16384 + t16);
    GLOAD_LDS16(bptr2 + (size_t)p * 32, lds + p * 32768 + 24576 + t16);
  }
  asm volatile("s_waitcnt vmcnt(8)" ::: "memory");
  PH_BAR();

  for (int kt = 0; kt < 125; ++kt) {
    KTILE(kt, 1);
    asm volatile("s_waitcnt vmcnt(8)" ::: "memory");  // kt+1 fully staged
    PH_BAR();
  }
  KTILE(125, 0);
  asm volatile("s_waitcnt vmcnt(4)" ::: "memory");
  PH_BAR();
  KTILE(126, 0);
  asm volatile("s_waitcnt vmcnt(0)" ::: "memory");
  PH_BAR();
  KTILE(127, 0);

  // epilogue: C/D layout col=lane&15, row=(lane>>4)*4+j ; store bf16
  const int colb = n0 + wn * 64 + (lane & 15);
  const int rowb = m0 + wm * 128 + (lane >> 4) * 4;
#pragma unroll
  for (int m_ = 0; m_ < 8; ++m_)
#pragma unroll
    for (int n_ = 0; n_ < 4; ++n_)
#pragma unroll
      for (int j = 0; j < 4; ++j)
        C[(size_t)(rowb + m_ * 16 + j) * 4096 + colb + n_ * 16] =
            f2bf_rne(acc[m_][n_][j]);
}

// ---------------- MFMA scores + softmax -> attn[256][64][64] f32 ------------
// Per head n: Qh = Qb[n*32768 ..] is [512 d][64 i] bf16 (i-fastest).
// scores[i,j] = (1/sqrt(512)) sum_d Qh[d][i] Kh[d][j].
// LDS chunk [64 th][64 i], granule rotation rot(th) = (th + 2*(th>>3)) & 7.
__device__ __forceinline__ bf16x8 load_frag_rot(const uint16_t* buf,
                                                int ij, int thb) {
  union { uint16_t u[8]; bf16x8 v; } r;
#pragma unroll
  for (int e = 0; e < 8; ++e) {
    const int th = thb + e;
    const int rot = (th + 2 * (th >> 3)) & 7;
    const int irot = (ij + rot * 8) & 63;
    r.u[e] = buf[th * 64 + irot];
  }
  return r.v;
}

__global__ __launch_bounds__(256) void attn_scores_mfma(
    const uint16_t* __restrict__ Qb, const uint16_t* __restrict__ Kb,
    float* __restrict__ attn) {
  const int n = blockIdx.x;
  __shared__ uint16_t q_l[2][4096];
  __shared__ uint16_t k_l[2][4096];
  __shared__ float scores_l[64 * 68];

  const int t = threadIdx.x;
  const int lane = t & 63;
  const int w = t >> 6;
  const int i0w = (w >> 1) * 32, j0w = (w & 1) * 32;

  const uint16_t* Qn = Qb + (size_t)n * 32768;
  const uint16_t* Kn = Kb + (size_t)n * 32768;

  const int g1 = t, g2 = t + 256;
  const int th1 = g1 >> 3, th2 = g2 >> 3;
  const int s1 = (((g1 & 7) - ((th1 + 2 * (th1 >> 3)) & 7)) & 7);
  const int s2 = (((g2 & 7) - ((th2 + 2 * (th2 >> 3)) & 7)) & 7);
  const size_t so1 = (size_t)th1 * 64 + s1 * 8;
  const size_t so2 = (size_t)th2 * 64 + s2 * 8;

#define STAGE_CH(bf, cm)                                                    \
  do {                                                                      \
    const size_t co_ = (size_t)(cm) * 4096;                                 \
    GLOAD_LDS16(Qn + co_ + so1, (char*)&q_l[bf][0] + g1 * 16);              \
    GLOAD_LDS16(Qn + co_ + so2, (char*)&q_l[bf][0] + g2 * 16);              \
    GLOAD_LDS16(Kn + co_ + so1, (char*)&k_l[bf][0] + g1 * 16);              \
    GLOAD_LDS16(Kn + co_ + so2, (char*)&k_l[bf][0] + g2 * 16);              \
  } while (0)

  f32x4 acc[2][2] = {};

  STAGE_CH(0, 0);
  asm volatile("s_waitcnt vmcnt(0)" ::: "memory");
  __syncthreads();

  for (int cm = 0; cm < 8; ++cm) {
    const int bf = cm & 1;
    if (cm < 7) STAGE_CH(bf ^ 1, cm + 1);
#pragma unroll
    for (int ks = 0; ks < 2; ++ks) {
      const int thb = ks * 32 + (lane >> 4) * 8;
      bf16x8 aa0 = load_frag_rot(&q_l[bf][0], i0w + (lane & 15), thb);
      bf16x8 aa1 = load_frag_rot(&q_l[bf][0], i0w + 16 + (lane & 15), thb);
      bf16x8 bb0 = load_frag_rot(&k_l[bf][0], j0w + (lane & 15), thb);
      bf16x8 bb1 = load_frag_rot(&k_l[bf][0], j0w + 16 + (lane & 15), thb);
      acc[0][0] = __builtin_amdgcn_mfma_f32_16x16x32_bf16(aa0, bb0, acc[0][0], 0, 0, 0);
      acc[0][1] = __builtin_amdgcn_mfma_f32_16x16x32_bf16(aa0, bb1, acc[0][1], 0, 0, 0);
      acc[1][0] = __builtin_amdgcn_mfma_f32_16x16x32_bf16(aa1, bb0, acc[1][0], 0, 0, 0);
      acc[1][1] = __builtin_amdgcn_mfma_f32_16x16x32_bf16(aa1, bb1, acc[1][1], 0, 0, 0);
    }
    asm volatile("s_waitcnt vmcnt(0)" ::: "memory");
    __syncthreads();
  }
#undef STAGE_CH

#pragma unroll
  for (int fi = 0; fi < 2; ++fi)
#pragma unroll
    for (int fj = 0; fj < 2; ++fj)
#pragma unroll
      for (int jr = 0; jr < 4; ++jr) {
        const int i = i0w + fi * 16 + (lane >> 4) * 4 + jr;
        const int j = j0w + fj * 16 + (lane & 15);
        scores_l[i * 68 + j] = acc[fi][fj][jr];
      }
  __syncthreads();

  {
    const int i = t >> 2, jg = t & 3;
    float pv[16];
    *(float4*)(pv + 0)  = *(const float4*)&scores_l[i * 68 + jg * 16 + 0];
    *(float4*)(pv + 4)  = *(const float4*)&scores_l[i * 68 + jg * 16 + 4];
    *(float4*)(pv + 8)  = *(const float4*)&scores_l[i * 68 + jg * 16 + 8];
    *(float4*)(pv + 12) = *(const float4*)&scores_l[i * 68 + jg * 16 + 12];
    float m = pv[0];
#pragma unroll
    for (int q = 1; q < 16; ++q) m = fmaxf(m, pv[q]);
    m = fmaxf(m, __shfl_xor(m, 1, 64));
    m = fmaxf(m, __shfl_xor(m, 2, 64));
    const float sc = 0.044194173824159216f * 1.4426950408889634f;
    float e[16];
    float ssum = 0.f;
#pragma unroll
    for (int q = 0; q < 16; ++q) {
      e[q] = exp2f((pv[q] - m) * sc);
      ssum += e[q];
    }
    ssum += __shfl_xor(ssum, 1, 64);
    ssum += __shfl_xor(ssum, 2, 64);
    const float inv = 1.0f / ssum;
    float ov[16];
#pragma unroll
    for (int q = 0; q < 16; ++q) ov[q] = e[q] * inv;
    float* dst = attn + (size_t)n * 4096 + i * 64 + jg * 16;
    *(float4*)(dst + 0)  = *(float4*)(ov + 0);
    *(float4*)(dst + 4)  = *(float4*)(ov + 4);
    *(float4*)(dst + 8)  = *(float4*)(ov + 8);
    *(float4*)(dst + 12) = *(float4*)(ov + 12);
  }
}

// ---------------- V = x-slab * Wv^T ; context = V @ attn ; leaky; scatter ----
__global__ __launch_bounds__(256) void ctx_kernel(
    const float* __restrict__ x, const float* __restrict__ Wv,
    const float* __restrict__ attn, float* __restrict__ out) {
  const int n = blockIdx.x >> 3, ut = blockIdx.x & 7;
  const int b = n >> 3, g = n & 7;
  const int u0 = ut * 64;
  __shared__ float attn_l[64 * 64];
  __shared__ float wv_l[64 * 64];
  __shared__ float x_l[64 * 64];
  __shared__ float v_l[64 * 64];
  const int t = threadIdx.x;

#pragma unroll
  for (int r = 0; r < 4; ++r) {
    ((float4*)attn_l)[r * 256 + t] =
        ((const float4*)(attn + (size_t)n * 4096))[r * 256 + t];
    ((float4*)wv_l)[r * 256 + t] = ((const float4*)Wv)[r * 256 + t];
  }
  {
    const float* xbase = x + (size_t)b * 262144 + (size_t)g * 512 + u0;
    const int ul4 = (t & 15) * 4;
    const int cc0 = t >> 4;
#pragma unroll
    for (int r = 0; r < 4; ++r) {
      int cc = cc0 + r * 16;
      *(float4*)&x_l[cc * 64 + ul4] = *(const float4*)&xbase[(size_t)cc * 4096 + ul4];
    }
  }
  __syncthreads();
  {
    const int ul = t & 63, e0 = t >> 6;
    float vacc[16];
#pragma unroll
    for (int ee = 0; ee < 16; ++ee) vacc[ee] = 0.f;
    for (int cc = 0; cc < 64; ++cc) {
      float xv = x_l[cc * 64 + ul];
#pragma unroll
      for (int ee = 0; ee < 16; ++ee)
        vacc[ee] += xv * wv_l[(e0 + 4 * ee) * 64 + cc];
    }
#pragma unroll
    for (int ee = 0; ee < 16; ++ee) v_l[(e0 + 4 * ee) * 64 + ul] = vacc[ee];
  }
  __syncthreads();
  {
    const int ul = t & 63, j0 = t >> 6;
    float cacc[16];
#pragma unroll
    for (int jj = 0; jj < 16; ++jj) cacc[jj] = 0.f;
    for (int c = 0; c < 64; ++c) {
      float vv = v_l[c * 64 + ul];
#pragma unroll
      for (int jj = 0; jj < 16; ++jj)
        cacc[jj] += vv * attn_l[c * 64 + j0 + 4 * jj];
    }
    float* ob = out + (size_t)b * 262144 + (size_t)g * 8 * 4096;
#pragma unroll
    for (int jj = 0; jj < 16; ++jj) {
      int j = j0 + 4 * jj;
      float v = cacc[jj];
      v = v > 0.f ? v : 0.2f * v;
      ob[(size_t)(j >> 3) * 4096 + (size_t)(j & 7) * 512 + u0 + ul] = v;
    }
  }
}

extern "C" void kernel_launch(void* const* d_in, const int* in_sizes, int n_in,
                              void* d_out, int out_size, void* d_ws, size_t ws_size,
                              hipStream_t stream) {
  const float* z  = (const float*)d_in[0];
  const float* x  = (const float*)d_in[1];
  const float* Wq = (const float*)d_in[2];
  const float* Wk = (const float*)d_in[3];
  const float* Wv = (const float*)d_in[4];
  float* out = (float*)d_out;

  char* ws = (char*)d_ws;
  uint16_t* zb   = (uint16_t*)(ws);                  // 16 MB
  uint16_t* wqb  = (uint16_t*)(ws + 16777216);       // 32 MB
  uint16_t* wkb  = (uint16_t*)(ws + 50331648);       // 32 MB
  uint16_t* qbo  = (uint16_t*)(ws + 83886080);       // 16 MB bf16 Q
  uint16_t* kbo  = (uint16_t*)(ws + 100663296);      // 16 MB bf16 K
  float*    attn = (float*)(ws + 117440512);         // 4 MB f32

  cvt_all<<<20480, 256, 0, stream>>>(z, Wq, Wk, zb, wqb, wkb);

  (void)hipFuncSetAttribute((const void*)gemm_qk8,
                            hipFuncAttributeMaxDynamicSharedMemorySize, 131072);
  dim3 ggrid(128, 2);
  gemm_qk8<<<ggrid, 512, 131072, stream>>>(zb, wqb, wkb, qbo, kbo);

  attn_scores_mfma<<<256, 256, 0, stream>>>(qbo, kbo, attn);
  ctx_kernel<<<2048, 256, 0, stream>>>(x, Wv, attn, out);
}

// Round 6
// 236.802 us; speedup vs baseline: 1.2331x; 1.0205x over previous
//
#include <hip/hip_runtime.h>
#include <hip/hip_bf16.h>
#include <stdint.h>

typedef __attribute__((ext_vector_type(8))) __bf16 bf16x8;
typedef __attribute__((ext_vector_type(4))) float f32x4;

#define GLOAD_LDS16(gp, lp) __builtin_amdgcn_global_load_lds( \
    (const __attribute__((address_space(1))) void*)(gp),      \
    (__attribute__((address_space(3))) void*)(lp), 16, 0, 0)

__device__ __forceinline__ uint16_t f2bf_rne(float f) {
  uint32_t u = __float_as_uint(f);
  u += 0x7FFFu + ((u >> 16) & 1u);
  return (uint16_t)(u >> 16);
}

// ---------------- fused f32 -> bf16 conversion (z, Wq, Wk in one launch) ----
__global__ __launch_bounds__(256) void cvt_all(
    const float* __restrict__ z, const float* __restrict__ wq,
    const float* __restrict__ wk, uint16_t* __restrict__ zb,
    uint16_t* __restrict__ wqb, uint16_t* __restrict__ wkb) {
  const int bid = blockIdx.x;
  const float* src;
  uint16_t* dst;
  int i;
  if (bid < 4096)        { src = z;  dst = zb;  i = bid * 256 + threadIdx.x; }
  else if (bid < 12288)  { src = wq; dst = wqb; i = (bid - 4096) * 256 + threadIdx.x; }
  else                   { src = wk; dst = wkb; i = (bid - 12288) * 256 + threadIdx.x; }
  const float4* s4 = (const float4*)src;
  float4 a = s4[2 * i], b = s4[2 * i + 1];
  union { uint16_t u[8]; uint4 v; } o;
  o.u[0] = f2bf_rne(a.x); o.u[1] = f2bf_rne(a.y);
  o.u[2] = f2bf_rne(a.z); o.u[3] = f2bf_rne(a.w);
  o.u[4] = f2bf_rne(b.x); o.u[5] = f2bf_rne(b.y);
  o.u[6] = f2bf_rne(b.z); o.u[7] = f2bf_rne(b.w);
  ((uint4*)dst)[i] = o.v;
}

// ---------------- bf16 GEMM, 256x256 tile, 16 waves, ring-4 BK=32 -----------
// R6: (a) 1024 threads / 16 waves (4x4), per-wave 64x64 -> acc 64 VGPR ->
//     4 waves/SIMD latency hiding; (b) bijective 2x4 XCD supertile so each
//     XCD touches A 8MB + B 16MB (was 66MB). Dataflow (ring-4, depth-3
//     prefetch, counted vmcnt, XOR swizzle, one barrier/K-tile, bf16
//     epilogue) is R5-validated.
#define PH_BAR() do { asm volatile("" ::: "memory");            \
                      __builtin_amdgcn_s_barrier();             \
                      asm volatile("" ::: "memory"); } while (0)

#define KTILE(kt, DO_STAGE)                                                    \
  do {                                                                         \
    const char* Ab_ = lds + ((kt) & 3) * 32768;                                \
    const char* Bb_ = Ab_ + 16384;                                             \
    bf16x8 aa[4], bb[4];                                                       \
    _Pragma("unroll")                                                          \
    for (int n_ = 0; n_ < 4; ++n_)                                             \
      bb[n_] = *(const bf16x8*)(Bb_ + boff + n_ * 1024);                       \
    _Pragma("unroll")                                                          \
    for (int m_ = 0; m_ < 4; ++m_)                                             \
      aa[m_] = *(const bf16x8*)(Ab_ + aoff + m_ * 1024);                       \
    if (DO_STAGE) {                                                            \
      const int ss_ = ((kt) + 3) & 3;                                          \
      GLOAD_LDS16(aptr + (size_t)((kt) + 3) * 32, lds + ss_ * 32768 + t16);    \
      GLOAD_LDS16(bptr + (size_t)((kt) + 3) * 32,                              \
                  lds + ss_ * 32768 + 16384 + t16);                            \
    }                                                                          \
    __builtin_amdgcn_s_setprio(1);                                             \
    _Pragma("unroll")                                                          \
    for (int m_ = 0; m_ < 4; ++m_)                                             \
      _Pragma("unroll")                                                        \
      for (int n_ = 0; n_ < 4; ++n_)                                           \
        acc[m_][n_] = __builtin_amdgcn_mfma_f32_16x16x32_bf16(                 \
            aa[m_], bb[n_], acc[m_][n_], 0, 0, 0);                             \
    __builtin_amdgcn_s_setprio(0);                                             \
  } while (0)

__global__ __launch_bounds__(1024, 4) void gemm_qk16(
    const uint16_t* __restrict__ A,
    const uint16_t* __restrict__ Bq, const uint16_t* __restrict__ Bk,
    uint16_t* __restrict__ Cq, uint16_t* __restrict__ Ck) {
  extern __shared__ char lds[];  // 131072 bytes: 4 ring slots x (A 16K + B 16K)

  // bijective supertile: xcd = gid&7 -> (tm half, tn quarter); 32 blocks/XCD
  const int gid = blockIdx.x;
  const int xcd = gid & 7;
  const int idx = gid >> 3;          // 0..31
  const int which = idx & 1;
  const int r = idx >> 1;            // 0..15
  const int tm = (xcd & 1) * 4 + (r & 3);
  const int tn = (xcd >> 1) * 4 + (r >> 2);

  const uint16_t* Bmat = which ? Bk : Bq;
  uint16_t* C = which ? Ck : Cq;
  const int m0 = tm * 256, n0 = tn * 256;

  const int t = threadIdx.x;
  const int lane = t & 63;
  const int w = t >> 6;              // 0..15
  const int wm = w >> 2, wn = w & 3; // 4x4 wave grid, each 64x64 output
  const int t16 = t * 16;

  // staging: thread t covers row t>>2, k-granule t&3 (pre-swizzled source)
  const int gsw = (((t & 3) ^ ((t >> 3) & 3)) * 8);
  const uint16_t* aptr = A    + (size_t)(m0 + (t >> 2)) * 4096 + gsw;
  const uint16_t* bptr = Bmat + (size_t)(n0 + (t >> 2)) * 4096 + gsw;

  // ds_read byte offsets (same XOR involution on the read side)
  const int sl = ((lane >> 4) ^ ((lane & 15) >> 1)) & 3;
  const int aoff = (wm * 64 + (lane & 15)) * 64 + sl * 16;
  const int boff = (wn * 64 + (lane & 15)) * 64 + sl * 16;

  f32x4 acc[4][4] = {};

  // prologue: stage K-tiles 0,1,2 (6 loads/thread); tile0 ready at vmcnt(4)
#pragma unroll
  for (int p = 0; p < 3; ++p) {
    GLOAD_LDS16(aptr + (size_t)p * 32, lds + p * 32768 + t16);
    GLOAD_LDS16(bptr + (size_t)p * 32, lds + p * 32768 + 16384 + t16);
  }
  asm volatile("s_waitcnt vmcnt(4)" ::: "memory");
  PH_BAR();

  for (int kt = 0; kt < 125; ++kt) {
    KTILE(kt, 1);
    asm volatile("s_waitcnt vmcnt(4)" ::: "memory");  // kt+1 fully staged
    PH_BAR();
  }
  KTILE(125, 0);
  asm volatile("s_waitcnt vmcnt(2)" ::: "memory");
  PH_BAR();
  KTILE(126, 0);
  asm volatile("s_waitcnt vmcnt(0)" ::: "memory");
  PH_BAR();
  KTILE(127, 0);

  // epilogue: C/D layout col=lane&15, row=(lane>>4)*4+j ; store bf16
  const int colb = n0 + wn * 64 + (lane & 15);
  const int rowb = m0 + wm * 64 + (lane >> 4) * 4;
#pragma unroll
  for (int m_ = 0; m_ < 4; ++m_)
#pragma unroll
    for (int n_ = 0; n_ < 4; ++n_)
#pragma unroll
      for (int j = 0; j < 4; ++j)
        C[(size_t)(rowb + m_ * 16 + j) * 4096 + colb + n_ * 16] =
            f2bf_rne(acc[m_][n_][j]);
}

// ---------------- MFMA scores + softmax -> attn[256][64][64] f32 ------------
// Per head n: Qh = Qb[n*32768 ..] is [512 d][64 i] bf16 (i-fastest).
// scores[i,j] = (1/sqrt(512)) sum_d Qh[d][i] Kh[d][j].
// LDS chunk [64 th][64 i], granule rotation rot(th) = (th + 2*(th>>3)) & 7.
__device__ __forceinline__ bf16x8 load_frag_rot(const uint16_t* buf,
                                                int ij, int thb) {
  union { uint16_t u[8]; bf16x8 v; } r;
#pragma unroll
  for (int e = 0; e < 8; ++e) {
    const int th = thb + e;
    const int rot = (th + 2 * (th >> 3)) & 7;
    const int irot = (ij + rot * 8) & 63;
    r.u[e] = buf[th * 64 + irot];
  }
  return r.v;
}

__global__ __launch_bounds__(256) void attn_scores_mfma(
    const uint16_t* __restrict__ Qb, const uint16_t* __restrict__ Kb,
    float* __restrict__ attn) {
  const int n = blockIdx.x;
  __shared__ uint16_t q_l[2][4096];
  __shared__ uint16_t k_l[2][4096];
  __shared__ float scores_l[64 * 68];

  const int t = threadIdx.x;
  const int lane = t & 63;
  const int w = t >> 6;
  const int i0w = (w >> 1) * 32, j0w = (w & 1) * 32;

  const uint16_t* Qn = Qb + (size_t)n * 32768;
  const uint16_t* Kn = Kb + (size_t)n * 32768;

  const int g1 = t, g2 = t + 256;
  const int th1 = g1 >> 3, th2 = g2 >> 3;
  const int s1 = (((g1 & 7) - ((th1 + 2 * (th1 >> 3)) & 7)) & 7);
  const int s2 = (((g2 & 7) - ((th2 + 2 * (th2 >> 3)) & 7)) & 7);
  const size_t so1 = (size_t)th1 * 64 + s1 * 8;
  const size_t so2 = (size_t)th2 * 64 + s2 * 8;

#define STAGE_CH(bf, cm)                                                    \
  do {                                                                      \
    const size_t co_ = (size_t)(cm) * 4096;                                 \
    GLOAD_LDS16(Qn + co_ + so1, (char*)&q_l[bf][0] + g1 * 16);              \
    GLOAD_LDS16(Qn + co_ + so2, (char*)&q_l[bf][0] + g2 * 16);              \
    GLOAD_LDS16(Kn + co_ + so1, (char*)&k_l[bf][0] + g1 * 16);              \
    GLOAD_LDS16(Kn + co_ + so2, (char*)&k_l[bf][0] + g2 * 16);              \
  } while (0)

  f32x4 acc[2][2] = {};

  STAGE_CH(0, 0);
  asm volatile("s_waitcnt vmcnt(0)" ::: "memory");
  __syncthreads();

  for (int cm = 0; cm < 8; ++cm) {
    const int bf = cm & 1;
    if (cm < 7) STAGE_CH(bf ^ 1, cm + 1);
#pragma unroll
    for (int ks = 0; ks < 2; ++ks) {
      const int thb = ks * 32 + (lane >> 4) * 8;
      bf16x8 aa0 = load_frag_rot(&q_l[bf][0], i0w + (lane & 15), thb);
      bf16x8 aa1 = load_frag_rot(&q_l[bf][0], i0w + 16 + (lane & 15), thb);
      bf16x8 bb0 = load_frag_rot(&k_l[bf][0], j0w + (lane & 15), thb);
      bf16x8 bb1 = load_frag_rot(&k_l[bf][0], j0w + 16 + (lane & 15), thb);
      acc[0][0] = __builtin_amdgcn_mfma_f32_16x16x32_bf16(aa0, bb0, acc[0][0], 0, 0, 0);
      acc[0][1] = __builtin_amdgcn_mfma_f32_16x16x32_bf16(aa0, bb1, acc[0][1], 0, 0, 0);
      acc[1][0] = __builtin_amdgcn_mfma_f32_16x16x32_bf16(aa1, bb0, acc[1][0], 0, 0, 0);
      acc[1][1] = __builtin_amdgcn_mfma_f32_16x16x32_bf16(aa1, bb1, acc[1][1], 0, 0, 0);
    }
    asm volatile("s_waitcnt vmcnt(0)" ::: "memory");
    __syncthreads();
  }
#undef STAGE_CH

#pragma unroll
  for (int fi = 0; fi < 2; ++fi)
#pragma unroll
    for (int fj = 0; fj < 2; ++fj)
#pragma unroll
      for (int jr = 0; jr < 4; ++jr) {
        const int i = i0w + fi * 16 + (lane >> 4) * 4 + jr;
        const int j = j0w + fj * 16 + (lane & 15);
        scores_l[i * 68 + j] = acc[fi][fj][jr];
      }
  __syncthreads();

  {
    const int i = t >> 2, jg = t & 3;
    float pv[16];
    *(float4*)(pv + 0)  = *(const float4*)&scores_l[i * 68 + jg * 16 + 0];
    *(float4*)(pv + 4)  = *(const float4*)&scores_l[i * 68 + jg * 16 + 4];
    *(float4*)(pv + 8)  = *(const float4*)&scores_l[i * 68 + jg * 16 + 8];
    *(float4*)(pv + 12) = *(const float4*)&scores_l[i * 68 + jg * 16 + 12];
    float m = pv[0];
#pragma unroll
    for (int q = 1; q < 16; ++q) m = fmaxf(m, pv[q]);
    m = fmaxf(m, __shfl_xor(m, 1, 64));
    m = fmaxf(m, __shfl_xor(m, 2, 64));
    const float sc = 0.044194173824159216f * 1.4426950408889634f;
    float e[16];
    float ssum = 0.f;
#pragma unroll
    for (int q = 0; q < 16; ++q) {
      e[q] = exp2f((pv[q] - m) * sc);
      ssum += e[q];
    }
    ssum += __shfl_xor(ssum, 1, 64);
    ssum += __shfl_xor(ssum, 2, 64);
    const float inv = 1.0f / ssum;
    float ov[16];
#pragma unroll
    for (int q = 0; q < 16; ++q) ov[q] = e[q] * inv;
    float* dst = attn + (size_t)n * 4096 + i * 64 + jg * 16;
    *(float4*)(dst + 0)  = *(float4*)(ov + 0);
    *(float4*)(dst + 4)  = *(float4*)(ov + 4);
    *(float4*)(dst + 8)  = *(float4*)(ov + 8);
    *(float4*)(dst + 12) = *(float4*)(ov + 12);
  }
}

// ---------------- V = x-slab * Wv^T ; context = V @ attn ; leaky; scatter ----
__global__ __launch_bounds__(256) void ctx_kernel(
    const float* __restrict__ x, const float* __restrict__ Wv,
    const float* __restrict__ attn, float* __restrict__ out) {
  const int n = blockIdx.x >> 3, ut = blockIdx.x & 7;
  const int b = n >> 3, g = n & 7;
  const int u0 = ut * 64;
  __shared__ float attn_l[64 * 64];
  __shared__ float wv_l[64 * 64];
  __shared__ float x_l[64 * 64];
  __shared__ float v_l[64 * 64];
  const int t = threadIdx.x;

#pragma unroll
  for (int r = 0; r < 4; ++r) {
    ((float4*)attn_l)[r * 256 + t] =
        ((const float4*)(attn + (size_t)n * 4096))[r * 256 + t];
    ((float4*)wv_l)[r * 256 + t] = ((const float4*)Wv)[r * 256 + t];
  }
  {
    const float* xbase = x + (size_t)b * 262144 + (size_t)g * 512 + u0;
    const int ul4 = (t & 15) * 4;
    const int cc0 = t >> 4;
#pragma unroll
    for (int r = 0; r < 4; ++r) {
      int cc = cc0 + r * 16;
      *(float4*)&x_l[cc * 64 + ul4] = *(const float4*)&xbase[(size_t)cc * 4096 + ul4];
    }
  }
  __syncthreads();
  {
    const int ul = t & 63, e0 = t >> 6;
    float vacc[16];
#pragma unroll
    for (int ee = 0; ee < 16; ++ee) vacc[ee] = 0.f;
    for (int cc = 0; cc < 64; ++cc) {
      float xv = x_l[cc * 64 + ul];
#pragma unroll
      for (int ee = 0; ee < 16; ++ee)
        vacc[ee] += xv * wv_l[(e0 + 4 * ee) * 64 + cc];
    }
#pragma unroll
    for (int ee = 0; ee < 16; ++ee) v_l[(e0 + 4 * ee) * 64 + ul] = vacc[ee];
  }
  __syncthreads();
  {
    const int ul = t & 63, j0 = t >> 6;
    float cacc[16];
#pragma unroll
    for (int jj = 0; jj < 16; ++jj) cacc[jj] = 0.f;
    for (int c = 0; c < 64; ++c) {
      float vv = v_l[c * 64 + ul];
#pragma unroll
      for (int jj = 0; jj < 16; ++jj)
        cacc[jj] += vv * attn_l[c * 64 + j0 + 4 * jj];
    }
    float* ob = out + (size_t)b * 262144 + (size_t)g * 8 * 4096;
#pragma unroll
    for (int jj = 0; jj < 16; ++jj) {
      int j = j0 + 4 * jj;
      float v = cacc[jj];
      v = v > 0.f ? v : 0.2f * v;
      ob[(size_t)(j >> 3) * 4096 + (size_t)(j & 7) * 512 + u0 + ul] = v;
    }
  }
}

extern "C" void kernel_launch(void* const* d_in, const int* in_sizes, int n_in,
                              void* d_out, int out_size, void* d_ws, size_t ws_size,
                              hipStream_t stream) {
  const float* z  = (const float*)d_in[0];
  const float* x  = (const float*)d_in[1];
  const float* Wq = (const float*)d_in[2];
  const float* Wk = (const float*)d_in[3];
  const float* Wv = (const float*)d_in[4];
  float* out = (float*)d_out;

  char* ws = (char*)d_ws;
  uint16_t* zb   = (uint16_t*)(ws);                  // 16 MB
  uint16_t* wqb  = (uint16_t*)(ws + 16777216);       // 32 MB
  uint16_t* wkb  = (uint16_t*)(ws + 50331648);       // 32 MB
  uint16_t* qbo  = (uint16_t*)(ws + 83886080);       // 16 MB bf16 Q
  uint16_t* kbo  = (uint16_t*)(ws + 100663296);      // 16 MB bf16 K
  float*    attn = (float*)(ws + 117440512);         // 4 MB f32

  cvt_all<<<20480, 256, 0, stream>>>(z, Wq, Wk, zb, wqb, wkb);

  (void)hipFuncSetAttribute((const void*)gemm_qk16,
                            hipFuncAttributeMaxDynamicSharedMemorySize, 131072);
  gemm_qk16<<<256, 1024, 131072, stream>>>(zb, wqb, wkb, qbo, kbo);

  attn_scores_mfma<<<256, 256, 0, stream>>>(qbo, kbo, attn);
  ctx_kernel<<<2048, 256, 0, stream>>>(x, Wv, attn, out);
}